// Round 7
// baseline (182.600 us; speedup 1.0000x reference)
//
#include <hip/hip_runtime.h>

// PointGatedBlock: SE3 point conv + gated nonlinearity. fp32 in/out.
// R16 = R15 (61.7us) restructured for 3 blocks/CU with NOTHING else changed:
// same grid 512 (8 n-rows/block), same reg-staged feat, same phi recurrence.
// LDS 67->52.3KB by single-buffering feat (phi stays double-buffered);
// 160/3=54.6KB limit met. Requires 2 barriers/iter: [A] tile s visible ->
// issue LOAD(s+1) -> GEMM1(s) ; [B] featb free -> phi(s+1)+feat(s+1) writes.
// Loads issue at GEMM1-phase start so their vmcnt drain at bar B has the
// whole MFMA phase as cover. fr/dm live ranges now within-iteration (were
// cross-barrier) -> natural VGPR drops; cap (512,6): 84 unified = 52 arch +
// 32 acc. Spill canary = WRITE_SIZE. Cross-block interleave (3 blocks)
// replaces the lost within-block phi||GEMM1 overlap.

typedef __attribute__((ext_vector_type(4))) float f32x4;
typedef __attribute__((ext_vector_type(8))) short s16x8;

#define DI 104
#define DO 144
#define TTST 1688          // Tt row stride (elems)
#define YST 9

#define W_ELEMS 239616     // 16*144*104
#define F_ELEMS 425984     // 4*104*1024

// LDS: phi dbl-buf 2x16K + feat single 14336 + y 5184 = 52288 -> 3 blocks/CU
#define OFF_PHI0 0
#define OFF_PHI1 16384
#define OFF_FEAT 32768                  // 112 rows x 64 x 2B (8 pad rows)
#define OFF_Y    47104
#define SMEM_TOTAL (47104 + 144*9*4)    // 52288 B

__device__ __forceinline__ float fexp2(float x) {
#if __has_builtin(__builtin_amdgcn_exp2f)
    return __builtin_amdgcn_exp2f(x);
#else
    return exp2f(x);
#endif
}
__device__ __forceinline__ float flog2(float x) {
#if __has_builtin(__builtin_amdgcn_logf)
    return __builtin_amdgcn_logf(x);
#else
    return log2f(x);
#endif
}
__device__ __forceinline__ float fsqrt_(float x) {
#if __has_builtin(__builtin_amdgcn_sqrtf)
    return __builtin_amdgcn_sqrtf(x);
#else
    return sqrtf(x);
#endif
}
__device__ __forceinline__ float frcp_(float x) {
#if __has_builtin(__builtin_amdgcn_rcpf)
    return __builtin_amdgcn_rcpf(x);
#else
    return 1.0f / x;
#endif
}
__device__ __forceinline__ unsigned int pkbf(float lo, float hi) {
    unsigned int a = __builtin_bit_cast(unsigned int, lo) + 0x8000u;
    unsigned int b = __builtin_bit_cast(unsigned int, hi) + 0x8000u;
    return __builtin_amdgcn_perm(b, a, 0x07060302u);
}
__device__ __forceinline__ unsigned short f2b(float f) {
    return (unsigned short)((__builtin_bit_cast(unsigned int, f) + 0x8000u) >> 16);
}

// ---- pre-kernel: fp32 -> bf16 for W (ws[0..W_ELEMS)) and feat (ws[W_ELEMS..)) ----
__global__ __launch_bounds__(256, 8)
void cvt_kernel(const float* __restrict__ feat_g, const float* __restrict__ W_g,
                unsigned short* __restrict__ ws)
{
    int gid = blockIdx.x * 256 + threadIdx.x;           // 8 elems per thread
    const float* src;
    unsigned short* dst;
    if (gid < W_ELEMS/8) {
        src = W_g + gid*8;  dst = ws + gid*8;
    } else {
        int g2 = gid - W_ELEMS/8;
        src = feat_g + g2*8; dst = ws + W_ELEMS + g2*8;
    }
    f32x4 a = *(const f32x4*)src;
    f32x4 b = *(const f32x4*)(src + 4);
    unsigned int o[4] = { pkbf(a[0],a[1]), pkbf(a[2],a[3]), pkbf(b[0],b[1]), pkbf(b[2],b[3]) };
    *(f32x4*)dst = *(f32x4*)o;
}

// load-tile macro: diff/mask regs for this thread's (n-row, 2 m cols) at m-base M0
#define LOAD_DM(M0)                                                    \
    do {                                                               \
        const float* dp_ = diff_g + (dmrow + (M0) + pml)*3;            \
        dx0 = dp_[0]; dy0 = dp_[1]; dz0 = dp_[2];                      \
        dx1 = dp_[3]; dy1 = dp_[4]; dz1 = dp_[5];                      \
        const float* mp_ = mask_g + dmrow + (M0) + pml;                \
        mk0 = mp_[0]; mk1 = mp_[1];                                    \
    } while (0)

#define LOAD_FEAT(M0)                                                          \
    do {                                                                       \
        fr0 = *(const s16x8*)(featbf + fbase + ((size_t)fi0 << 10) + (M0) + (fj << 3)); \
        if (t < 320)                                                           \
            fr1 = *(const s16x8*)(featbf + fbase + ((size_t)fi1 << 10) + (M0) + (fj << 3)); \
    } while (0)

// phi for this thread's 8 k's (half kh) x 2 m-cols via exact multiplicative
// finite differences: exp2(E_{j+1}) = exp2(E_j)*exp2(s_j), exp2(s_{j+1}) =
// exp2(s_j)*2^V2. 8 transcendentals (2 sqrt, 2 log2, 4 exp2) vs 20 naive.
#define COMPUTE_WRITE_PHI(BUF)                                         \
    do {                                                               \
        unsigned short* pw_ = (BUF) + phirow;                          \
        float r0_ = fsqrt_(fmaf(dx0,dx0, fmaf(dy0,dy0, fmaf(dz0,dz0, 1e-12f)))); \
        float r1_ = fsqrt_(fmaf(dx1,dx1, fmaf(dy1,dy1, fmaf(dz1,dz1, 1e-12f)))); \
        float t0_ = r0_ - K0OFF, t1_ = r1_ - K0OFF;                    \
        float v0_ = fexp2(fmaf(CEXP*t0_, t0_, flog2(mk0)));            \
        float v1_ = fexp2(fmaf(CEXP*t1_, t1_, flog2(mk1)));            \
        float w0_ = fexp2(fmaf(A1, r0_, S0B));                         \
        float w1_ = fexp2(fmaf(A1, r1_, S0B));                         \
        *(unsigned int*)(pw_ + (pblk << 3)) = pkbf(v0_, v1_);          \
        _Pragma("unroll")                                              \
        for (int j_ = 1; j_ < 8; ++j_) {                               \
            v0_ *= w0_; w0_ *= U2;                                     \
            v1_ *= w1_; w1_ *= U2;                                     \
            *(unsigned int*)(pw_ + j_*64 + ((pblk ^ j_) << 3)) = pkbf(v0_, v1_); \
        }                                                              \
    } while (0)

#define WRITE_FEAT(BUF)                                                \
    do {                                                               \
        *(s16x8*)((BUF) + fi0*64 + fjs) = fr0;                         \
        if (t < 320) *(s16x8*)((BUF) + fi1*64 + fjs) = fr1;            \
    } while (0)

#define GEMM1(PBUF, FBUF)                                              \
    do {                                                               \
        _Pragma("unroll")                                              \
        for (int kk_ = 0; kk_ < 2; ++kk_) {                            \
            const int mo_ = ((kk_*4 + q) ^ sw) << 3;                   \
            s16x8 a0_ = *(const s16x8*)((PBUF) + ((2*wr    )*16 + l15)*64 + mo_); \
            s16x8 a1_ = *(const s16x8*)((PBUF) + ((2*wr + 1)*16 + l15)*64 + mo_); \
            _Pragma("unroll")                                          \
            for (int cc_ = 0; cc_ < 4; ++cc_) {                        \
                if (ct0 + cc_ < 7) {                                   \
                    s16x8 bf_ = *(const s16x8*)((FBUF) + ((ct0+cc_)*16 + l15)*64 + mo_); \
                    acc[0][cc_] = __builtin_amdgcn_mfma_f32_16x16x32_bf16(a0_, bf_, acc[0][cc_], 0, 0, 0); \
                    acc[1][cc_] = __builtin_amdgcn_mfma_f32_16x16x32_bf16(a1_, bf_, acc[1][cc_], 0, 0, 0); \
                }                                                      \
            }                                                          \
        }                                                              \
    } while (0)

__global__ __launch_bounds__(512, 6)
void pgb_kernel(const unsigned short* __restrict__ ws,   // Wbf | featbf
                const float* __restrict__ diff_g,
                const float* __restrict__ mask_g,
                float* __restrict__ out_g)
{
    const unsigned short* Wbf    = ws;
    const unsigned short* featbf = ws + W_ELEMS;

    __shared__ __align__(16) unsigned char smem[SMEM_TOTAL];
    unsigned short* Tt   = (unsigned short*)smem;        // aliases phi bufs (post-loop)
    float*          ylds = (float*)(smem + OFF_Y);
    unsigned short* phi0b = (unsigned short*)(smem + OFF_PHI0);
    unsigned short* phi1b = (unsigned short*)(smem + OFF_PHI1);
    unsigned short* featb = (unsigned short*)(smem + OFF_FEAT);

    const int t    = threadIdx.x;
    const int b    = blockIdx.x >> 7;
    const int n0   = (blockIdx.x & 127) << 3;
    const int wave = t >> 6;
    const int lane = t & 63;
    const int l15  = lane & 15;
    const int q    = lane >> 4;
    const int wr   = wave >> 1;          // rowgroup: rowtiles 2wr, 2wr+1 (n_local)
    const int ct0  = (wave & 1) << 2;    // colgroup: coltiles ct0..ct0+3 (skip 7)
    const int sw   = l15 & 7;            // read-side swizzle key (row&7)

    // zero feat pad rows 104..111 (1KB)
    if (t < 256) ((unsigned int*)(smem + OFF_FEAT + DI*128))[t] = 0u;

    f32x4 acc[2][4];
#pragma unroll
    for (int rr = 0; rr < 2; ++rr)
#pragma unroll
        for (int cc = 0; cc < 4; ++cc)
            acc[rr][cc] = (f32x4){0.f, 0.f, 0.f, 0.f};

    // phi thread mapping: 8 n x 2 k-halves x 32 m-pairs
    const int pn   = t >> 6;             // n-row 0..7 (== wave)
    const int kh   = (t >> 5) & 1;       // k-half: k0 = 8*kh
    const int pml  = (t & 31) << 1;      // m pair (even), 0..62
    const int pblk = (t & 31) >> 2;      // m block 0..7 (write-side swizzle base)
    const int phirow = (pn*16 + kh*8)*64 + (pml & 7);   // phi write base (elems)
    const float CEXP = -23.083120654223414f;   // -GAMMA * log2(e)
    const float A1   = 6.155498841126244f;     // -2*CEXP*DL
    const float V2   = -0.8207331788168325f;   // 2*CEXP*DL^2
    const float U2   = fexp2(V2);              // 2^V2 (uniform)
    const float K0OFF = kh ? 1.0666666666666667f : 0.f;
    const float S0B   = kh ? -6.976232019943076f : -0.41036658940841624f;
    const size_t dmrow = (size_t)((b << 10) + n0 + pn) << 10;

    // feat staging mapping
    const int fi0 = t >> 3, fj = t & 7;
    const int fi1 = 64 + (t >> 3);
    const int fjs = (fj ^ (fi0 & 7)) << 3;
    const size_t fbase = (size_t)b * DI << 10;

    float dx0, dy0, dz0, dx1, dy1, dz1, mk0, mk1;
    s16x8 fr0 = {}, fr1 = {};

    // ---- prologue: load + write tile 0 (block-local, published by bar A(0))
    LOAD_DM(0);
    LOAD_FEAT(0);
    COMPUTE_WRITE_PHI(phi0b);
    WRITE_FEAT(featb);

    // ---- main loop: 2 barriers/iter.
    // [A] tile s visible -> issue loads(s+1) -> GEMM1(s) (drain at B = full cover)
    // [B] featb + phi[(s+1)&1] free -> phi(s+1)+feat(s+1) writes
    for (int s = 0; s < 16; ++s) {
        __syncthreads();                                  // A
        if (s < 15) {
            const int mn = (s + 1) << 6;
            LOAD_DM(mn);
            LOAD_FEAT(mn);
        }
        GEMM1((s & 1) ? phi1b : phi0b, featb);            // tile s
        __syncthreads();                                  // B
        if (s < 15) {
            COMPUTE_WRITE_PHI((s & 1) ? phi0b : phi1b);   // phi(s+1)
            WRITE_FEAT(featb);                            // feat(s+1)
        }
    }
    // after bar B(15): all GEMM1 reads done -> phi bufs free for Tt

    // ---- acc (C: col=l15=i_local, row=q*4+r=k; tiles (n_local, i-tile)) -> Tt[n][k*104+i]
#pragma unroll
    for (int rr = 0; rr < 2; ++rr) {
        int nloc = 2*wr + rr;
#pragma unroll
        for (int cc = 0; cc < 4; ++cc) {
            int i = (ct0+cc)*16 + l15;
            if (ct0 + cc < 7 && i < DI) {
#pragma unroll
                for (int r = 0; r < 4; ++r)
                    Tt[nloc*TTST + (q*4+r)*DI + i] = f2b(acc[rr][cc][r]);
            }
        }
    }
    __syncthreads();

    // ---- GEMM2: y[o,n] = sum_ki Wbf[k,o,i]*Tt[n][ki]; 52 K-steps of 32 ----
    f32x4 y0 = (f32x4){0.f,0.f,0.f,0.f}, y1 = (f32x4){0.f,0.f,0.f,0.f};
    const int o0 = wave*16 + l15;
    const int o1 = 128 + l15;            // o-tile 8, wave 0's second acc
#pragma unroll 4
    for (int s3 = 0; s3 < 52; ++s3) {
        int a = s3*4 + q;                // 8-elem ki block; k=a/13, i=(a%13)*8
        int k = a / 13;
        int i = (a - k*13) << 3;
        s16x8 bf = *(const s16x8*)(Tt + (l15 & 7)*TTST + s3*32 + q*8);
        s16x8 af = *(const s16x8*)(Wbf + (size_t)(k*DO + o0)*DI + i);
        y0 = __builtin_amdgcn_mfma_f32_16x16x32_bf16(af, bf, y0, 0, 0, 0);
        if (wave == 0) {
            s16x8 ag = *(const s16x8*)(Wbf + (size_t)(k*DO + o1)*DI + i);
            y1 = __builtin_amdgcn_mfma_f32_16x16x32_bf16(ag, bf, y1, 0, 0, 0);
        }
    }
    if (l15 < 8) {
#pragma unroll
        for (int r = 0; r < 4; ++r)
            ylds[(wave*16 + q*4 + r)*YST + l15] = y0[r];
        if (wave == 0) {
#pragma unroll
            for (int r = 0; r < 4; ++r)
                ylds[(128 + q*4 + r)*YST + l15] = y1[r];
        }
    }
    __syncthreads();

    // ---- gating epilogue: out[b, o(<120), n0+nn] fp32 ----
    const float L2E = 1.4426950408889634f;
    for (int idx = t; idx < 120*8; idx += 512) {
        int o = idx >> 3, nn = idx & 7;
        float y = ylds[o*YST + nn];
        float v;
        if (o < 32) {
            v = fmaxf(y, 0.f);
        } else if (o < 80) {
            float g = ylds[(120 + (o-32)/3)*YST + nn];
            v = y * frcp_(1.f + fexp2(-g*L2E));
        } else {
            float g = ylds[(136 + (o-80)/5)*YST + nn];
            v = y * frcp_(1.f + fexp2(-g*L2E));
        }
        out_g[((size_t)(b*120 + o) << 10) + n0 + nn] = v;
    }
}

extern "C" void kernel_launch(void* const* d_in, const int* in_sizes, int n_in,
                              void* d_out, int out_size, void* d_ws, size_t ws_size,
                              hipStream_t stream) {
    const float* feat = (const float*)d_in[0];  // [4,104,1024] fp32
    const float* diff = (const float*)d_in[1];  // [4,1024,1024,3] fp32
    const float* mask = (const float*)d_in[2];  // [4,1024,1024] fp32
    const float* W    = (const float*)d_in[3];  // [16,144,104] fp32
    float* out = (float*)d_out;                 // [4,120,1024] fp32
    unsigned short* ws = (unsigned short*)d_ws; // Wbf (479 KB) + featbf (852 KB)
    (void)in_sizes; (void)n_in; (void)out_size; (void)ws_size;
    cvt_kernel<<<dim3((W_ELEMS + F_ELEMS)/8/256), dim3(256), 0, stream>>>(feat, W, ws);
    pgb_kernel<<<dim3(512), dim3(512), 0, stream>>>(ws, diff, mask, out);
}

// Round 9
// 141.423 us; speedup vs baseline: 1.2912x; 1.2912x over previous
//
#include <hip/hip_runtime.h>

// PointGatedBlock: SE3 point conv + gated nonlinearity. fp32 in/out.
// R18 = R17 with the NaN fixed. R17's closed-form chain-B anchor computed
// w0^4 which overflows to inf for r > 5.27 (A1*r+S0B > 32); at such r the
// v-anchor has underflowed to 0 -> 0*inf = NaN (a handful per 4.2M pairs).
// Fix: clamp the 4th power to finite (fminf(w0^2*w0^2, 3e38)). When the
// clamp engages va0 is provably 0 (v-exponent < -640), so vb0 = 0 exactly
// as the true (underflowed) phi. Sequential chains were immune; R15 passed.
// Structure (unchanged from R17): interleaved iter body so each wave
// co-issues trans/ds_read/MFMA -- WRITE_FEAT -> PHI_ANCHOR -> GEMM1(kk=0) ->
// phi quadA -> GEMM1(kk=1) -> phi quadB -> loads(s+2). Phi = 2 independent
// 4-step chains (8 trans/thread). Grid 512, 8 n-rows, reg-staged feat,
// phi+feat double-buffered, 1 barrier/iter, 67KB LDS, 2 blk/CU, (512,4).

typedef __attribute__((ext_vector_type(4))) float f32x4;
typedef __attribute__((ext_vector_type(8))) short s16x8;

#define DI 104
#define DO 144
#define TTST 1688          // Tt row stride (elems)
#define YST 9

#define W_ELEMS 239616     // 16*144*104
#define F_ELEMS 425984     // 4*104*1024

// LDS byte offsets (phi/feat rows: 64 elems = 128 B, XOR-swizzled blocks)
#define OFF_PHI0 0
#define OFF_PHI1 16384                  // 128*64*2
#define OFF_FEAT0 32768
#define OFF_FEAT1 47104                 // + 112*64*2 = 14336
#define OFF_Y 61440
#define SMEM_TOTAL (61440 + 144*9*4)    // 66624 B -> 2 blocks/CU

__device__ __forceinline__ float fexp2(float x) {
#if __has_builtin(__builtin_amdgcn_exp2f)
    return __builtin_amdgcn_exp2f(x);
#else
    return exp2f(x);
#endif
}
__device__ __forceinline__ float flog2(float x) {
#if __has_builtin(__builtin_amdgcn_logf)
    return __builtin_amdgcn_logf(x);
#else
    return log2f(x);
#endif
}
__device__ __forceinline__ float fsqrt_(float x) {
#if __has_builtin(__builtin_amdgcn_sqrtf)
    return __builtin_amdgcn_sqrtf(x);
#else
    return sqrtf(x);
#endif
}
__device__ __forceinline__ float frcp_(float x) {
#if __has_builtin(__builtin_amdgcn_rcpf)
    return __builtin_amdgcn_rcpf(x);
#else
    return 1.0f / x;
#endif
}
__device__ __forceinline__ unsigned int pkbf(float lo, float hi) {
    unsigned int a = __builtin_bit_cast(unsigned int, lo) + 0x8000u;
    unsigned int b = __builtin_bit_cast(unsigned int, hi) + 0x8000u;
    return __builtin_amdgcn_perm(b, a, 0x07060302u);
}
__device__ __forceinline__ unsigned short f2b(float f) {
    return (unsigned short)((__builtin_bit_cast(unsigned int, f) + 0x8000u) >> 16);
}

// ---- pre-kernel: fp32 -> bf16 for W (ws[0..W_ELEMS)) and feat (ws[W_ELEMS..)) ----
__global__ __launch_bounds__(256, 8)
void cvt_kernel(const float* __restrict__ feat_g, const float* __restrict__ W_g,
                unsigned short* __restrict__ ws)
{
    int gid = blockIdx.x * 256 + threadIdx.x;           // 8 elems per thread
    const float* src;
    unsigned short* dst;
    if (gid < W_ELEMS/8) {
        src = W_g + gid*8;  dst = ws + gid*8;
    } else {
        int g2 = gid - W_ELEMS/8;
        src = feat_g + g2*8; dst = ws + W_ELEMS + g2*8;
    }
    f32x4 a = *(const f32x4*)src;
    f32x4 b = *(const f32x4*)(src + 4);
    unsigned int o[4] = { pkbf(a[0],a[1]), pkbf(a[2],a[3]), pkbf(b[0],b[1]), pkbf(b[2],b[3]) };
    *(f32x4*)dst = *(f32x4*)o;
}

// load-tile macro: diff/mask regs for this thread's (n-row, 2 m cols) at m-base M0
#define LOAD_DM(M0)                                                    \
    do {                                                               \
        const float* dp_ = diff_g + (dmrow + (M0) + pml)*3;            \
        dx0 = dp_[0]; dy0 = dp_[1]; dz0 = dp_[2];                      \
        dx1 = dp_[3]; dy1 = dp_[4]; dz1 = dp_[5];                      \
        const float* mp_ = mask_g + dmrow + (M0) + pml;                \
        mk0 = mp_[0]; mk1 = mp_[1];                                    \
    } while (0)

#define LOAD_FEAT(M0)                                                          \
    do {                                                                       \
        fr0 = *(const s16x8*)(featbf + fbase + ((size_t)fi0 << 10) + (M0) + (fj << 3)); \
        if (t < 320)                                                           \
            fr1 = *(const s16x8*)(featbf + fbase + ((size_t)fi1 << 10) + (M0) + (fj << 3)); \
    } while (0)

// phi anchors for this thread's 8 k's (half kh) x 2 m-cols: chain A (k 0-3)
// anchors va/wa via 4 exp2; chain B (k 4-7) anchors derived via muls:
// v4 = v0*w0^4*U2_6, w4 = w0*U2_4 (exact closed form). The 4th power is
// CLAMPED to finite: when it would exceed 3e38, va is provably 0 (its
// exponent < -640) so vb = 0 exactly -- avoids 0*inf = NaN (R17 bug).
#define PHI_ANCHOR()                                                   \
    do {                                                               \
        float r0_ = fsqrt_(fmaf(dx0,dx0, fmaf(dy0,dy0, fmaf(dz0,dz0, 1e-12f)))); \
        float r1_ = fsqrt_(fmaf(dx1,dx1, fmaf(dy1,dy1, fmaf(dz1,dz1, 1e-12f)))); \
        float t0_ = r0_ - K0OFF, t1_ = r1_ - K0OFF;                    \
        va0 = fexp2(fmaf(CEXP*t0_, t0_, flog2(mk0)));                  \
        va1 = fexp2(fmaf(CEXP*t1_, t1_, flog2(mk1)));                  \
        wa0 = fexp2(fmaf(A1, r0_, S0B));                               \
        wa1 = fexp2(fmaf(A1, r1_, S0B));                               \
        float p0_ = wa0*wa0, p1_ = wa1*wa1;                            \
        float q0_ = fminf(p0_*p0_, 3.0e38f);                           \
        float q1_ = fminf(p1_*p1_, 3.0e38f);                           \
        vb0 = va0 * q0_ * U2_6;                                        \
        vb1 = va1 * q1_ * U2_6;                                        \
        wb0 = wa0 * U2_4;                                              \
        wb1 = wa1 * U2_4;                                              \
    } while (0)

// write one 4-k quad (rows J0..J0+3) from its chain; v,w advanced in place
#define PHI_WRITE_Q(BUF, V0, V1, W0, W1, J0)                           \
    do {                                                               \
        unsigned short* pw_ = (BUF) + phirow;                          \
        _Pragma("unroll")                                              \
        for (int j_ = 0; j_ < 4; ++j_) {                               \
            *(unsigned int*)(pw_ + ((J0) + j_)*64 + ((pblk ^ ((J0) + j_)) << 3)) = pkbf(V0, V1); \
            V0 *= W0; W0 *= U2;                                        \
            V1 *= W1; W1 *= U2;                                        \
        }                                                              \
    } while (0)

#define WRITE_FEAT(BUF)                                                \
    do {                                                               \
        *(s16x8*)((BUF) + fi0*64 + fjs) = fr0;                         \
        if (t < 320) *(s16x8*)((BUF) + fi1*64 + fjs) = fr1;            \
    } while (0)

// one kk-half of GEMM1 (2 A-reads, up to 4 B-reads, up to 8 MFMAs)
#define GEMM1_HALF(PBUF, FBUF, KK)                                     \
    do {                                                               \
        const int mo_ = (((KK)*4 + q) ^ sw) << 3;                      \
        s16x8 a0_ = *(const s16x8*)((PBUF) + ((2*wr    )*16 + l15)*64 + mo_); \
        s16x8 a1_ = *(const s16x8*)((PBUF) + ((2*wr + 1)*16 + l15)*64 + mo_); \
        _Pragma("unroll")                                              \
        for (int cc_ = 0; cc_ < 4; ++cc_) {                            \
            if (ct0 + cc_ < 7) {                                       \
                s16x8 bf_ = *(const s16x8*)((FBUF) + ((ct0+cc_)*16 + l15)*64 + mo_); \
                acc[0][cc_] = __builtin_amdgcn_mfma_f32_16x16x32_bf16(a0_, bf_, acc[0][cc_], 0, 0, 0); \
                acc[1][cc_] = __builtin_amdgcn_mfma_f32_16x16x32_bf16(a1_, bf_, acc[1][cc_], 0, 0, 0); \
            }                                                          \
        }                                                              \
    } while (0)

__global__ __launch_bounds__(512, 4)
void pgb_kernel(const unsigned short* __restrict__ ws,   // Wbf | featbf
                const float* __restrict__ diff_g,
                const float* __restrict__ mask_g,
                float* __restrict__ out_g)
{
    const unsigned short* Wbf    = ws;
    const unsigned short* featbf = ws + W_ELEMS;

    __shared__ __align__(16) unsigned char smem[SMEM_TOTAL];
    unsigned short* Tt   = (unsigned short*)smem;        // aliases phi bufs (post-barrier)
    float*          ylds = (float*)(smem + OFF_Y);
    unsigned short* phi0b  = (unsigned short*)(smem + OFF_PHI0);
    unsigned short* phi1b  = (unsigned short*)(smem + OFF_PHI1);
    unsigned short* feat0b = (unsigned short*)(smem + OFF_FEAT0);
    unsigned short* feat1b = (unsigned short*)(smem + OFF_FEAT1);

    const int t    = threadIdx.x;
    const int b    = blockIdx.x >> 7;
    const int n0   = (blockIdx.x & 127) << 3;
    const int wave = t >> 6;
    const int lane = t & 63;
    const int l15  = lane & 15;
    const int q    = lane >> 4;
    const int wr   = wave >> 1;          // rowgroup: rowtiles 2wr, 2wr+1 (n_local)
    const int ct0  = (wave & 1) << 2;    // colgroup: coltiles ct0..ct0+3 (skip 7)
    const int sw   = l15 & 7;            // read-side swizzle key (row&7)

    // zero feat pad rows 104..111 in both buffers
    if (t < 256) {
        ((unsigned int*)(smem + OFF_FEAT0 + DI*128))[t] = 0u;
        ((unsigned int*)(smem + OFF_FEAT1 + DI*128))[t] = 0u;
    }

    f32x4 acc[2][4];
#pragma unroll
    for (int rr = 0; rr < 2; ++rr)
#pragma unroll
        for (int cc = 0; cc < 4; ++cc)
            acc[rr][cc] = (f32x4){0.f, 0.f, 0.f, 0.f};

    // phi thread mapping: 8 n x 2 k-halves x 32 m-pairs
    const int pn   = t >> 6;             // n-row 0..7 (== wave)
    const int kh   = (t >> 5) & 1;       // k-half: k0 = 8*kh
    const int pml  = (t & 31) << 1;      // m pair (even), 0..62
    const int pblk = (t & 31) >> 2;      // m block 0..7 (write-side swizzle base)
    const int phirow = (pn*16 + kh*8)*64 + (pml & 7);   // phi write base (elems)
    const float CEXP = -23.083120654223414f;   // -GAMMA * log2(e)
    const float A1   = 6.155498841126244f;     // -2*CEXP*DL
    const float V2   = -0.8207331788168325f;   // 2*CEXP*DL^2
    const float U2   = fexp2(V2);              // 2^V2 (uniform)
    const float U2_2 = U2*U2;
    const float U2_4 = U2_2*U2_2;              // 2^(4 V2)
    const float U2_6 = U2_4*U2_2;              // 2^(6 V2)
    const float K0OFF = kh ? 1.0666666666666667f : 0.f;
    const float S0B   = kh ? -6.976232019943076f : -0.41036658940841624f;
    const size_t dmrow = (size_t)((b << 10) + n0 + pn) << 10;

    // feat staging mapping
    const int fi0 = t >> 3, fj = t & 7;
    const int fi1 = 64 + (t >> 3);
    const int fjs = (fj ^ (fi0 & 7)) << 3;
    const size_t fbase = (size_t)b * DI << 10;

    float dx0, dy0, dz0, dx1, dy1, dz1, mk0, mk1;
    s16x8 fr0 = {}, fr1 = {};
    float va0, va1, wa0, wa1, vb0, vb1, wb0, wb1;

    // ---- prologue: tile 0 -> buf0; then preload tile 1 regs ----
    LOAD_DM(0);
    LOAD_FEAT(0);
    PHI_ANCHOR();
    PHI_WRITE_Q(phi0b, va0, va1, wa0, wa1, 0);
    PHI_WRITE_Q(phi0b, vb0, vb1, wb0, wb1, 4);
    WRITE_FEAT(feat0b);
    LOAD_DM(64);
    LOAD_FEAT(64);

    // ---- main loop: iter s reads buf(s&1), writes tile s+1 -> buf(~s&1).
    // Interleaved body: feat write -> phi anchors (trans chains launch) ->
    // GEMM1 kk=0 -> phi quadA -> GEMM1 kk=1 -> phi quadB -> loads(s+2).
    for (int s = 0; s < 15; ++s) {
        unsigned short* rp = (s & 1) ? phi1b  : phi0b;
        unsigned short* rf = (s & 1) ? feat1b : feat0b;
        unsigned short* wp = (s & 1) ? phi0b  : phi1b;
        unsigned short* wf = (s & 1) ? feat0b : feat1b;
        __syncthreads();
        WRITE_FEAT(wf);                 // tile s+1 from fr regs (before reload)
        PHI_ANCHOR();                   // tile s+1 from dm regs (before reload)
        GEMM1_HALF(rp, rf, 0);          // tile s, independent of phi
        PHI_WRITE_Q(wp, va0, va1, wa0, wa1, 0);
        GEMM1_HALF(rp, rf, 1);
        PHI_WRITE_Q(wp, vb0, vb1, wb0, wb1, 4);
        {
            const int mnext = (s < 14 ? (s + 2) : 15) * 64;
            LOAD_DM(mnext);             // consumed next iter -> full-iter cover
            LOAD_FEAT(mnext);
        }
    }
    __syncthreads();
    GEMM1_HALF(phi1b, feat1b, 0);       // tail: tile 15 lives in buf1
    GEMM1_HALF(phi1b, feat1b, 1);

    __syncthreads();   // phi bufs free -> Tt may overwrite

    // ---- acc (C: col=l15=i_local, row=q*4+r=k; tiles (n_local, i-tile)) -> Tt[n][k*104+i]
#pragma unroll
    for (int rr = 0; rr < 2; ++rr) {
        int nloc = 2*wr + rr;
#pragma unroll
        for (int cc = 0; cc < 4; ++cc) {
            int i = (ct0+cc)*16 + l15;
            if (ct0 + cc < 7 && i < DI) {
#pragma unroll
                for (int r = 0; r < 4; ++r)
                    Tt[nloc*TTST + (q*4+r)*DI + i] = f2b(acc[rr][cc][r]);
            }
        }
    }
    __syncthreads();

    // ---- GEMM2: y[o,n] = sum_ki Wbf[k,o,i]*Tt[n][ki]; 52 K-steps of 32 ----
    f32x4 y0 = (f32x4){0.f,0.f,0.f,0.f}, y1 = (f32x4){0.f,0.f,0.f,0.f};
    const int o0 = wave*16 + l15;
    const int o1 = 128 + l15;            // o-tile 8, wave 0's second acc
#pragma unroll 4
    for (int s3 = 0; s3 < 52; ++s3) {
        int a = s3*4 + q;                // 8-elem ki block; k=a/13, i=(a%13)*8
        int k = a / 13;
        int i = (a - k*13) << 3;
        s16x8 bf = *(const s16x8*)(Tt + (l15 & 7)*TTST + s3*32 + q*8);
        s16x8 af = *(const s16x8*)(Wbf + (size_t)(k*DO + o0)*DI + i);
        y0 = __builtin_amdgcn_mfma_f32_16x16x32_bf16(af, bf, y0, 0, 0, 0);
        if (wave == 0) {
            s16x8 ag = *(const s16x8*)(Wbf + (size_t)(k*DO + o1)*DI + i);
            y1 = __builtin_amdgcn_mfma_f32_16x16x32_bf16(ag, bf, y1, 0, 0, 0);
        }
    }
    if (l15 < 8) {
#pragma unroll
        for (int r = 0; r < 4; ++r)
            ylds[(wave*16 + q*4 + r)*YST + l15] = y0[r];
        if (wave == 0) {
#pragma unroll
            for (int r = 0; r < 4; ++r)
                ylds[(128 + q*4 + r)*YST + l15] = y1[r];
        }
    }
    __syncthreads();

    // ---- gating epilogue: out[b, o(<120), n0+nn] fp32 ----
    const float L2E = 1.4426950408889634f;
    for (int idx = t; idx < 120*8; idx += 512) {
        int o = idx >> 3, nn = idx & 7;
        float y = ylds[o*YST + nn];
        float v;
        if (o < 32) {
            v = fmaxf(y, 0.f);
        } else if (o < 80) {
            float g = ylds[(120 + (o-32)/3)*YST + nn];
            v = y * frcp_(1.f + fexp2(-g*L2E));
        } else {
            float g = ylds[(136 + (o-80)/5)*YST + nn];
            v = y * frcp_(1.f + fexp2(-g*L2E));
        }
        out_g[((size_t)(b*120 + o) << 10) + n0 + nn] = v;
    }
}

extern "C" void kernel_launch(void* const* d_in, const int* in_sizes, int n_in,
                              void* d_out, int out_size, void* d_ws, size_t ws_size,
                              hipStream_t stream) {
    const float* feat = (const float*)d_in[0];  // [4,104,1024] fp32
    const float* diff = (const float*)d_in[1];  // [4,1024,1024,3] fp32
    const float* mask = (const float*)d_in[2];  // [4,1024,1024] fp32
    const float* W    = (const float*)d_in[3];  // [16,144,104] fp32
    float* out = (float*)d_out;                 // [4,120,1024] fp32
    unsigned short* ws = (unsigned short*)d_ws; // Wbf (479 KB) + featbf (852 KB)
    (void)in_sizes; (void)n_in; (void)out_size; (void)ws_size;
    cvt_kernel<<<dim3((W_ELEMS + F_ELEMS)/8/256), dim3(256), 0, stream>>>(feat, W, ws);
    pgb_kernel<<<dim3(512), dim3(512), 0, stream>>>(ws, diff, mask, out);
}